// Round 9
// baseline (186.676 us; speedup 1.0000x reference)
//
#include <hip/hip_runtime.h>
#include <hip/hip_bf16.h>

// FullAttention: N=2, L=S=2048, H=16, E=D=64, fp32 in/out, additive mask.
// R16: R14 base (verified 152.3us: NS=1 combine-free, tri-buffer KV,
// vmcnt(4)+s_barrier 2-ahead staging, sb-major lagged-exp QK) + the mask-prep
// pass DELETED: attn reads M directly in fp32 (8x dwordx4/lane/tile,
// prefetched 1 tile ahead), C-init multiplies by SCALE_LOG2E in place of the
// bf16 unpack. Removes 2048 prep blocks + 25MB prep traffic + Mg buffer;
// mask no longer rounded to bf16. R15's barrier-halving REVERTED (regressed:
// it dropped counted-vmcnt, exposing stage latency at every barrier).

typedef short bf16x8 __attribute__((ext_vector_type(8)));
typedef short short4v __attribute__((ext_vector_type(4)));
typedef unsigned uint2v __attribute__((ext_vector_type(2)));
typedef float f32x4 __attribute__((ext_vector_type(4)));

constexpr int Nb = 2, Lq = 2048, Sk = 2048, Hh = 16, Ee = 64, Dd = 64;
constexpr int BM = 128;     // Q rows per block (4 waves x 32)
constexpr int BN = 64;      // K/V rows per S-tile
constexpr int NT = Sk / BN; // 32 tiles
constexpr int KVB = 4096;   // KV prep blocks
constexpr float SCALE_LOG2E = 0.125f * 1.4426950408889634f;  // (1/sqrt(64)) * log2(e)

__device__ __forceinline__ short f2bf(float f) {
  union { float f; unsigned u; } v; v.f = f;
  unsigned r = (v.u + 0x7fffu + ((v.u >> 16) & 1u)) >> 16;  // RNE
  return (short)r;
}

__device__ __forceinline__ unsigned pack_bf16x2(float a, float b) {
  union { __hip_bfloat162 h; unsigned u; } v;
  float2 f; f.x = a; f.y = b;
  v.h = __float22bfloat162_rn(f);
  return v.u;
}

__device__ __forceinline__ void async_copy16(const void* g, void* l) {
  __builtin_amdgcn_global_load_lds(
      (const __attribute__((address_space(1))) unsigned int*)g,
      (__attribute__((address_space(3))) unsigned int*)l, 16, 0, 0);
}

// KV tile layout (8192 shorts = 16KB) -- UNCHANGED:
//   [0,4096): K chunks (sb,kc) of 512 shorts: lane l (c=l&15,quad=l>>4) holds
//             K[s=16sb+c][e=32kc+8quad+j], j=0..7  (x32 A-frag, b128 reads)
//   [4096,8192): V chunks (db*2+sbp) of 512 shorts: lane l holds 8 shorts:
//             k=0..7 -> V^T[d=16db+c][s=32sbp+16*(k>>2)+4quad+(k&3)]
//             (two x16 A-frags per b128 read)
__global__ __launch_bounds__(256) void prep_all(const float* __restrict__ K,
                                                const float* __restrict__ V,
                                                short* __restrict__ KVf) {
  int gid = blockIdx.x * 256 + threadIdx.x;  // 8-short unit index
  int off8 = gid & 1023;                     // unit within 8192-short tile
  int t  = (gid >> 10) & 31;
  int nh = gid >> 15;
  int n = nh >> 4, h = nh & 15;
  short* dst = KVf + ((size_t)(nh * NT + t)) * 8192 + off8 * 8;
  if (off8 < 512) {             // K region
    int ch = off8 >> 6;         // chunk 0..7: sb=ch>>1, kc=ch&1
    int l  = off8 & 63;
    int sb = ch >> 1, kc = ch & 1, c = l & 15, quad = l >> 4;
    const float* p = K + (((size_t)n * Sk + (t * 64 + sb * 16 + c)) * Hh + h) * Ee
                       + kc * 32 + quad * 8;
    float4 x = *(const float4*)(p);
    float4 y = *(const float4*)(p + 4);
    bf16x8 o;
    o[0] = f2bf(x.x); o[1] = f2bf(x.y); o[2] = f2bf(x.z); o[3] = f2bf(x.w);
    o[4] = f2bf(y.x); o[5] = f2bf(y.y); o[6] = f2bf(y.z); o[7] = f2bf(y.w);
    *(bf16x8*)dst = o;
  } else {                      // V region
    int pos = off8 - 512;       // 0..511
    int chunk = pos >> 6;       // db*2 + sbp
    int l = pos & 63;
    int db = chunk >> 1, sbp = chunk & 1, cc = l & 15, quad = l >> 4;
    const float* pbase = V + (((size_t)n * Sk + (t * 64 + sbp * 32 + quad * 4)) * Hh + h) * Dd
                           + db * 16 + cc;
    bf16x8 o;
#pragma unroll
    for (int k = 0; k < 8; ++k) {
      int s_off = (k >> 2) * 16 + (k & 3);   // 16*sbi + j
      o[k] = f2bf(pbase[(size_t)s_off * Hh * Dd]);
    }
    *(bf16x8*)dst = o;
  }
}

__global__ __launch_bounds__(256, 2) void attn_fwd(
    const float* __restrict__ Q, const short* __restrict__ KVf,
    const float* __restrict__ M, float* __restrict__ Out)
{
  __shared__ short KV[3][8192];   // K+V fragment tile, triple-buffered (48KB)

  const int tid  = threadIdx.x;
  const int lane = tid & 63;
  const int w    = tid >> 6;     // wave 0..3
  const int quad = lane >> 4;    // 0..3
  const int c    = lane & 15;    // 0..15

  // XCD-aware decode: XCD (id&7) hosts 4 nh values -> KV set 2.1MB fits L2.
  const int id   = blockIdx.x;
  const int slot = id >> 3;              // 0..63
  const int nh   = (id & 7) * 4 + (slot & 3);
  const int qt   = (slot >> 2) & 15;     // 16 q-tiles of 128 rows
  const int n    = nh >> 4;
  const int h    = nh & 15;

  const int row0 = qt * BM + w * 32;     // wave's first global q row
  constexpr int tc = NT;                 // all 32 tiles -- full row-sum owned

  // ---- Q fragments, pre-scaled (B-operand x32 layout), 2 q-rows per lane ----
  bf16x8 qfrag[2][2];   // [cb][kc]
#pragma unroll
  for (int cb = 0; cb < 2; ++cb) {
    const float* qp = Q + (((size_t)n * Lq + (row0 + cb * 16 + c)) * Hh + h) * Ee;
#pragma unroll
    for (int kc = 0; kc < 2; ++kc) {
      const float* p = qp + kc * 32 + quad * 8;
      float4 x = *(const float4*)(p);
      float4 y = *(const float4*)(p + 4);
      bf16x8 f;
      f[0] = f2bf(x.x * SCALE_LOG2E); f[1] = f2bf(x.y * SCALE_LOG2E);
      f[2] = f2bf(x.z * SCALE_LOG2E); f[3] = f2bf(x.w * SCALE_LOG2E);
      f[4] = f2bf(y.x * SCALE_LOG2E); f[5] = f2bf(y.y * SCALE_LOG2E);
      f[6] = f2bf(y.z * SCALE_LOG2E); f[7] = f2bf(y.w * SCALE_LOG2E);
      qfrag[cb][kc] = f;
    }
  }

  // O^T accumulator: o[cb][db][r] = O[q=row0+cb*16+c][d = db*16 + quad*4 + r]
  f32x4 o[2][4];
#pragma unroll
  for (int cb = 0; cb < 2; ++cb)
#pragma unroll
    for (int db = 0; db < 4; ++db) { o[cb][db][0] = 0.f; o[cb][db][1] = 0.f; o[cb][db][2] = 0.f; o[cb][db][3] = 0.f; }
  float rs[2] = {0.f, 0.f};

  const short* kvt = KVf + (size_t)nh * NT * 8192;
  // mask rows for this lane: fp32, direct from M (shared across nh -> L2/L3)
  const float* mrow0 = M + (size_t)(row0 + c) * Sk + quad * 4;
  const float* mrow1 = mrow0 + (size_t)16 * Sk;

  // ---- prologue: mask t0 -> mcur (fp32); stage tiles 0 (buf0), 1 (buf1) ----
  f32x4 mcur[8];   // [cb*4+sb]
#pragma unroll
  for (int sb = 0; sb < 4; ++sb) {
    mcur[sb]     = *(const f32x4*)(mrow0 + sb * 16);
    mcur[4 + sb] = *(const f32x4*)(mrow1 + sb * 16);
  }
#pragma unroll
  for (int i = 0; i < 4; ++i) {
    int seg = w * 4 + i;
    async_copy16(kvt + seg * 512 + lane * 8, &KV[0][seg * 512 + lane * 8]);
  }
#pragma unroll
  for (int i = 0; i < 4; ++i) {
    int seg = w * 4 + i;
    async_copy16(kvt + 8192 + seg * 512 + lane * 8, &KV[1][seg * 512 + lane * 8]);
  }
  // stage(t0) complete (only stage(t0+1)'s 4 ops may remain in flight)
  asm volatile("s_waitcnt vmcnt(4)" ::: "memory");
  __builtin_amdgcn_s_barrier();

  int bR = 0;   // LDS buffer holding tile tt
  for (int tt = 0; tt < tc; ++tt) {
    const short* kb = &KV[bR][0];

    // ---- C-init: sacc[cb][sb][r] = M * SCALE_LOG2E at
    //      s = 16sb + 4quad + r, q = row0 + cb*16 + c ----
    f32x4 sacc[2][4];
#pragma unroll
    for (int cb = 0; cb < 2; ++cb)
#pragma unroll
      for (int sb = 0; sb < 4; ++sb) {
        f32x4 m = mcur[cb * 4 + sb];
        sacc[cb][sb][0] = m[0] * SCALE_LOG2E;
        sacc[cb][sb][1] = m[1] * SCALE_LOG2E;
        sacc[cb][sb][2] = m[2] * SCALE_LOG2E;
        sacc[cb][sb][3] = m[3] * SCALE_LOG2E;
      }

    // ---- prefetch: mask t+1 reloads mcur in place (8 dwordx4, FIRST);
    //      stage t+2 -> freed buffer (4 async ops, LAST) ----
    if (tt + 1 < tc) {
      const int co = (tt + 1) * 64;
#pragma unroll
      for (int sb = 0; sb < 4; ++sb) {
        mcur[sb]     = *(const f32x4*)(mrow0 + co + sb * 16);
        mcur[4 + sb] = *(const f32x4*)(mrow1 + co + sb * 16);
      }
    }
    if (tt + 2 < tc) {
      int bW = bR + 2; if (bW >= 3) bW -= 3;
      const short* gk = kvt + (size_t)(tt + 2) * 8192;
      short* lw = &KV[bW][0];
#pragma unroll
      for (int i = 0; i < 4; ++i) {
        int seg = w * 4 + i;
        async_copy16(gk + seg * 512 + lane * 8, &lw[seg * 512 + lane * 8]);
      }
    }

    // ---- S^T = K Q^T, sb-major, exp/pack(sb-1) lagged under MFMAs(sb) ----
    short4v pv[2][4];
#pragma unroll
    for (int sb = 0; sb < 4; ++sb) {
      bf16x8 kf0 = *(const bf16x8*)&kb[(sb * 2 + 0) * 512 + lane * 8];
      bf16x8 kf1 = *(const bf16x8*)&kb[(sb * 2 + 1) * 512 + lane * 8];
#pragma unroll
      for (int cb = 0; cb < 2; ++cb) {
        sacc[cb][sb] = __builtin_amdgcn_mfma_f32_16x16x32_bf16(kf0, qfrag[cb][0], sacc[cb][sb], 0, 0, 0);
        sacc[cb][sb] = __builtin_amdgcn_mfma_f32_16x16x32_bf16(kf1, qfrag[cb][1], sacc[cb][sb], 0, 0, 0);
      }
      if (sb > 0) {
        const int sl = sb - 1;
#pragma unroll
        for (int cb = 0; cb < 2; ++cb) {
          float p0 = __builtin_amdgcn_exp2f(sacc[cb][sl][0]);
          float p1 = __builtin_amdgcn_exp2f(sacc[cb][sl][1]);
          float p2 = __builtin_amdgcn_exp2f(sacc[cb][sl][2]);
          float p3 = __builtin_amdgcn_exp2f(sacc[cb][sl][3]);
          rs[cb] += (p0 + p1) + (p2 + p3);
          union { uint2v u; short4v s; } uu;
          uu.u.x = pack_bf16x2(p0, p1);
          uu.u.y = pack_bf16x2(p2, p3);
          pv[cb][sl] = uu.s;
        }
      }
    }
#pragma unroll
    for (int cb = 0; cb < 2; ++cb) {
      float p0 = __builtin_amdgcn_exp2f(sacc[cb][3][0]);
      float p1 = __builtin_amdgcn_exp2f(sacc[cb][3][1]);
      float p2 = __builtin_amdgcn_exp2f(sacc[cb][3][2]);
      float p3 = __builtin_amdgcn_exp2f(sacc[cb][3][3]);
      rs[cb] += (p0 + p1) + (p2 + p3);
      union { uint2v u; short4v s; } uu;
      uu.u.x = pack_bf16x2(p0, p1);
      uu.u.y = pack_bf16x2(p2, p3);
      pv[cb][3] = uu.s;
    }

    // ---- O^T += V^T P^T : x16 MFMAs, A = V frags (b128 pairs), B = pv regs ----
#pragma unroll
    for (int db = 0; db < 4; ++db) {
#pragma unroll
      for (int sbp = 0; sbp < 2; ++sbp) {
        bf16x8 vv = *(const bf16x8*)&kb[4096 + (db * 2 + sbp) * 512 + lane * 8];
        short4v v0, v1;
        v0[0] = vv[0]; v0[1] = vv[1]; v0[2] = vv[2]; v0[3] = vv[3];
        v1[0] = vv[4]; v1[1] = vv[5]; v1[2] = vv[6]; v1[3] = vv[7];
#pragma unroll
        for (int cb = 0; cb < 2; ++cb) {
          o[cb][db] = __builtin_amdgcn_mfma_f32_16x16x16bf16_1k(v0, pv[cb][sbp * 2 + 0], o[cb][db], 0, 0, 0);
          o[cb][db] = __builtin_amdgcn_mfma_f32_16x16x16bf16_1k(v1, pv[cb][sbp * 2 + 1], o[cb][db], 0, 0, 0);
        }
      }
    }

    // ---- counted-vmcnt barrier: only stage(t+2)'s 4 ops may stay in flight.
    //      Forces stage(t+1) + mask(t+1) complete (they were issued earlier).
    asm volatile("s_waitcnt vmcnt(4)" ::: "memory");
    __builtin_amdgcn_s_barrier();
    bR += 1; if (bR == 3) bR = 0;
  }

  // ---- epilogue: full row-sum owned -> normalize in-register, write Out ----
#pragma unroll
  for (int cb = 0; cb < 2; ++cb) {
    float v = rs[cb];
    v += __shfl_xor(v, 16, 64);
    v += __shfl_xor(v, 32, 64);
    const float inv = 1.0f / v;
    const int qrow = row0 + cb * 16 + c;
    float* op = Out + (((size_t)n * Lq + qrow) * Hh + h) * Dd + quad * 4;
#pragma unroll
    for (int db = 0; db < 4; ++db) {
      float4 ov;
      ov.x = o[cb][db][0] * inv; ov.y = o[cb][db][1] * inv;
      ov.z = o[cb][db][2] * inv; ov.w = o[cb][db][3] * inv;
      *(float4*)(op + db * 16) = ov;
    }
  }
}

extern "C" void kernel_launch(void* const* d_in, const int* in_sizes, int n_in,
                              void* d_out, int out_size, void* d_ws, size_t ws_size,
                              hipStream_t stream) {
  const float* Q   = (const float*)d_in[0];
  const float* K   = (const float*)d_in[1];
  const float* V   = (const float*)d_in[2];
  const float* Msk = (const float*)d_in[3];
  float* Out = (float*)d_out;

  short* KVf = (short*)d_ws;                         // 16.78 MB

  prep_all<<<dim3(KVB), dim3(256), 0, stream>>>(K, V, KVf);
  attn_fwd<<<dim3(512), dim3(256), 0, stream>>>(Q, KVf, Msk, Out);
}

// Round 10
// 150.508 us; speedup vs baseline: 1.2403x; 1.2403x over previous
//
#include <hip/hip_runtime.h>
#include <hip/hip_bf16.h>

// FullAttention: N=2, L=S=2048, H=16, E=D=64, fp32 in/out, additive mask.
// R17 = R14 verbatim (verified best, 152.27us): NS=1 combine-free attn
// (each block owns full row-sums, normalizes in-register, writes final Out),
// tri-buffered KV staged 2 ahead via global_load_lds with vmcnt(4)+s_barrier,
// sb-major QK with lagged exp/pack, bf16-staged lane-contiguous mask stream.
// R15 (barrier halving) and R16 (direct-fp32 mask) both REVERTED: measured
// regressions (+7us scheduling, +38us mask de-coalescing).

typedef short bf16x8 __attribute__((ext_vector_type(8)));
typedef short short4v __attribute__((ext_vector_type(4)));
typedef unsigned uint2v __attribute__((ext_vector_type(2)));
typedef unsigned uint4v __attribute__((ext_vector_type(4)));
typedef float f32x4 __attribute__((ext_vector_type(4)));

constexpr int Nb = 2, Lq = 2048, Sk = 2048, Hh = 16, Ee = 64, Dd = 64;
constexpr int BM = 128;     // Q rows per block (4 waves x 32)
constexpr int BN = 64;      // K/V rows per S-tile
constexpr int NT = Sk / BN; // 32 tiles
constexpr int KVB = 4096;   // KV prep blocks
constexpr int MSKB = 2048;  // mask prep blocks
constexpr float SCALE_LOG2E = 0.125f * 1.4426950408889634f;  // (1/sqrt(64)) * log2(e)

__device__ __forceinline__ short f2bf(float f) {
  union { float f; unsigned u; } v; v.f = f;
  unsigned r = (v.u + 0x7fffu + ((v.u >> 16) & 1u)) >> 16;  // RNE
  return (short)r;
}

__device__ __forceinline__ unsigned pack_bf16x2(float a, float b) {
  union { __hip_bfloat162 h; unsigned u; } v;
  float2 f; f.x = a; f.y = b;
  v.h = __float22bfloat162_rn(f);
  return v.u;
}

__device__ __forceinline__ float bf_lo(unsigned u) { return __uint_as_float(u << 16); }
__device__ __forceinline__ float bf_hi(unsigned u) { return __uint_as_float(u & 0xffff0000u); }

__device__ __forceinline__ void async_copy16(const void* g, void* l) {
  __builtin_amdgcn_global_load_lds(
      (const __attribute__((address_space(1))) unsigned int*)g,
      (__attribute__((address_space(3))) unsigned int*)l, 16, 0, 0);
}

// KV tile layout (8192 shorts = 16KB):
//   [0,4096): K chunks (sb,kc) of 512 shorts: lane l (c=l&15,quad=l>>4) holds
//             K[s=16sb+c][e=32kc+8quad+j], j=0..7  (x32 A-frag, b128 reads)
//   [4096,8192): V chunks (db*2+sbp) of 512 shorts: lane l holds 8 shorts:
//             k=0..7 -> V^T[d=16db+c][s=32sbp+16*(k>>2)+4quad+(k&3)]
//             (two x16 A-frags per b128 read)
__global__ __launch_bounds__(256) void prep_all(const float* __restrict__ K,
                                                const float* __restrict__ V,
                                                const float* __restrict__ M,
                                                short* __restrict__ KVf,
                                                short* __restrict__ Mg) {
  if (blockIdx.x < KVB) {
    int gid = blockIdx.x * 256 + threadIdx.x;  // 8-short unit index
    int off8 = gid & 1023;                     // unit within 8192-short tile
    int t  = (gid >> 10) & 31;
    int nh = gid >> 15;
    int n = nh >> 4, h = nh & 15;
    short* dst = KVf + ((size_t)(nh * NT + t)) * 8192 + off8 * 8;
    if (off8 < 512) {             // K region
      int ch = off8 >> 6;         // chunk 0..7: sb=ch>>1, kc=ch&1
      int l  = off8 & 63;
      int sb = ch >> 1, kc = ch & 1, c = l & 15, quad = l >> 4;
      const float* p = K + (((size_t)n * Sk + (t * 64 + sb * 16 + c)) * Hh + h) * Ee
                         + kc * 32 + quad * 8;
      float4 x = *(const float4*)(p);
      float4 y = *(const float4*)(p + 4);
      bf16x8 o;
      o[0] = f2bf(x.x); o[1] = f2bf(x.y); o[2] = f2bf(x.z); o[3] = f2bf(x.w);
      o[4] = f2bf(y.x); o[5] = f2bf(y.y); o[6] = f2bf(y.z); o[7] = f2bf(y.w);
      *(bf16x8*)dst = o;
    } else {                      // V region
      int pos = off8 - 512;       // 0..511
      int chunk = pos >> 6;       // db*2 + sbp
      int l = pos & 63;
      int db = chunk >> 1, sbp = chunk & 1, cc = l & 15, quad = l >> 4;
      const float* pbase = V + (((size_t)n * Sk + (t * 64 + sbp * 32 + quad * 4)) * Hh + h) * Dd
                             + db * 16 + cc;
      bf16x8 o;
#pragma unroll
      for (int k = 0; k < 8; ++k) {
        int s_off = (k >> 2) * 16 + (k & 3);   // 16*sbi + j
        o[k] = f2bf(pbase[(size_t)s_off * Hh * Dd]);
      }
      *(bf16x8*)dst = o;
    }
  } else {
    // Mask -> bf16*SCALE_LOG2E, lane-contiguous fragment order (BM=128):
    // short idx = ((((qt*4+w)*32+t)*64+lane)*4 + (cb*2+sbp))*8
    // unit (8 shorts) = [sb=2sbp: r0..r3][sb=2sbp+1: r0..r3]
    int u = (blockIdx.x - KVB) * 256 + threadIdx.x;   // 0..524287
    int sub  = u & 3;            // cb*2 + sbp
    int lane = (u >> 2) & 63;
    int t    = (u >> 8) & 31;
    int qw   = u >> 13;          // qt*4 + w  (0..63)
    int cb = sub >> 1, sbp = sub & 1;
    int c = lane & 15, quad = lane >> 4;
    int row = (qw >> 2) * 128 + (qw & 3) * 32 + cb * 16 + c;
    short o[8];
#pragma unroll
    for (int k = 0; k < 2; ++k) {
      int sb = sbp * 2 + k;
      float4 mv = *(const float4*)(M + (size_t)row * Sk + t * 64 + sb * 16 + quad * 4);
      o[k * 4 + 0] = f2bf(mv.x * SCALE_LOG2E);
      o[k * 4 + 1] = f2bf(mv.y * SCALE_LOG2E);
      o[k * 4 + 2] = f2bf(mv.z * SCALE_LOG2E);
      o[k * 4 + 3] = f2bf(mv.w * SCALE_LOG2E);
    }
    *(bf16x8*)(Mg + (size_t)u * 8) = *(const bf16x8*)o;
  }
}

__global__ __launch_bounds__(256, 2) void attn_fwd(
    const float* __restrict__ Q, const short* __restrict__ KVf,
    const short* __restrict__ Mg, float* __restrict__ Out)
{
  __shared__ short KV[3][8192];   // K+V fragment tile, triple-buffered (48KB)

  const int tid  = threadIdx.x;
  const int lane = tid & 63;
  const int w    = tid >> 6;     // wave 0..3
  const int quad = lane >> 4;    // 0..3
  const int c    = lane & 15;    // 0..15

  // XCD-aware decode: XCD (id&7) hosts 4 nh values -> KV set 2.1MB fits L2.
  const int id   = blockIdx.x;
  const int slot = id >> 3;              // 0..63
  const int nh   = (id & 7) * 4 + (slot & 3);
  const int qt   = (slot >> 2) & 15;     // 16 q-tiles of 128 rows
  const int n    = nh >> 4;
  const int h    = nh & 15;

  const int row0 = qt * BM + w * 32;     // wave's first global q row
  constexpr int tc = NT;                 // all 32 tiles -- full row-sum owned

  // ---- Q fragments, pre-scaled (B-operand x32 layout), 2 q-rows per lane ----
  bf16x8 qfrag[2][2];   // [cb][kc]
#pragma unroll
  for (int cb = 0; cb < 2; ++cb) {
    const float* qp = Q + (((size_t)n * Lq + (row0 + cb * 16 + c)) * Hh + h) * Ee;
#pragma unroll
    for (int kc = 0; kc < 2; ++kc) {
      const float* p = qp + kc * 32 + quad * 8;
      float4 x = *(const float4*)(p);
      float4 y = *(const float4*)(p + 4);
      bf16x8 f;
      f[0] = f2bf(x.x * SCALE_LOG2E); f[1] = f2bf(x.y * SCALE_LOG2E);
      f[2] = f2bf(x.z * SCALE_LOG2E); f[3] = f2bf(x.w * SCALE_LOG2E);
      f[4] = f2bf(y.x * SCALE_LOG2E); f[5] = f2bf(y.y * SCALE_LOG2E);
      f[6] = f2bf(y.z * SCALE_LOG2E); f[7] = f2bf(y.w * SCALE_LOG2E);
      qfrag[cb][kc] = f;
    }
  }

  // O^T accumulator: o[cb][db][r] = O[q=row0+cb*16+c][d = db*16 + quad*4 + r]
  f32x4 o[2][4];
#pragma unroll
  for (int cb = 0; cb < 2; ++cb)
#pragma unroll
    for (int db = 0; db < 4; ++db) { o[cb][db][0] = 0.f; o[cb][db][1] = 0.f; o[cb][db][2] = 0.f; o[cb][db][3] = 0.f; }
  float rs[2] = {0.f, 0.f};

  const short* kvt = KVf + (size_t)nh * NT * 8192;
  // mask stream: 65536 shorts per (qt,w); 2048 per tile; 32 per lane
  const short* mbase = Mg + (size_t)(qt * 4 + w) * 65536 + lane * 32;

  // ---- prologue: mask t0 -> mcur; stage tiles 0 (buf0) and 1 (buf1) ----
  uint4v mcur[4];
#pragma unroll
  for (int i = 0; i < 4; ++i) mcur[i] = *(const uint4v*)(mbase + i * 8);
#pragma unroll
  for (int i = 0; i < 4; ++i) {
    int seg = w * 4 + i;
    async_copy16(kvt + seg * 512 + lane * 8, &KV[0][seg * 512 + lane * 8]);
  }
#pragma unroll
  for (int i = 0; i < 4; ++i) {
    int seg = w * 4 + i;
    async_copy16(kvt + 8192 + seg * 512 + lane * 8, &KV[1][seg * 512 + lane * 8]);
  }
  // stage(t0) complete (only stage(t0+1)'s 4 ops may remain in flight)
  asm volatile("s_waitcnt vmcnt(4)" ::: "memory");
  __builtin_amdgcn_s_barrier();

  int bR = 0;   // LDS buffer holding tile tt
  for (int tt = 0; tt < tc; ++tt) {
    const short* kb = &KV[bR][0];

    // ---- C-init from mcur: sacc[cb][sb][r] = mask*SL at
    //      s = 16sb + 4quad + r, q = row0 + cb*16 + c ----
    f32x4 sacc[2][4];
#pragma unroll
    for (int cb = 0; cb < 2; ++cb)
#pragma unroll
      for (int sbp = 0; sbp < 2; ++sbp) {
        uint4v m = mcur[cb * 2 + sbp];
        sacc[cb][sbp * 2 + 0][0] = bf_lo(m.x); sacc[cb][sbp * 2 + 0][1] = bf_hi(m.x);
        sacc[cb][sbp * 2 + 0][2] = bf_lo(m.y); sacc[cb][sbp * 2 + 0][3] = bf_hi(m.y);
        sacc[cb][sbp * 2 + 1][0] = bf_lo(m.z); sacc[cb][sbp * 2 + 1][1] = bf_hi(m.z);
        sacc[cb][sbp * 2 + 1][2] = bf_lo(m.w); sacc[cb][sbp * 2 + 1][3] = bf_hi(m.w);
      }

    // ---- prefetch: mask t+1 reloads mcur in place (4 loads, issued FIRST);
    //      stage t+2 -> freed buffer (4 async ops, issued LAST) ----
    if (tt + 1 < tc) {
      const short* gm = mbase + (size_t)(tt + 1) * 2048;
#pragma unroll
      for (int i = 0; i < 4; ++i) mcur[i] = *(const uint4v*)(gm + i * 8);
    }
    if (tt + 2 < tc) {
      int bW = bR + 2; if (bW >= 3) bW -= 3;
      const short* gk = kvt + (size_t)(tt + 2) * 8192;
      short* lw = &KV[bW][0];
#pragma unroll
      for (int i = 0; i < 4; ++i) {
        int seg = w * 4 + i;
        async_copy16(gk + seg * 512 + lane * 8, &lw[seg * 512 + lane * 8]);
      }
    }

    // ---- S^T = K Q^T, sb-major, exp/pack(sb-1) lagged under MFMAs(sb) ----
    short4v pv[2][4];
#pragma unroll
    for (int sb = 0; sb < 4; ++sb) {
      bf16x8 kf0 = *(const bf16x8*)&kb[(sb * 2 + 0) * 512 + lane * 8];
      bf16x8 kf1 = *(const bf16x8*)&kb[(sb * 2 + 1) * 512 + lane * 8];
#pragma unroll
      for (int cb = 0; cb < 2; ++cb) {
        sacc[cb][sb] = __builtin_amdgcn_mfma_f32_16x16x32_bf16(kf0, qfrag[cb][0], sacc[cb][sb], 0, 0, 0);
        sacc[cb][sb] = __builtin_amdgcn_mfma_f32_16x16x32_bf16(kf1, qfrag[cb][1], sacc[cb][sb], 0, 0, 0);
      }
      if (sb > 0) {
        const int sl = sb - 1;
#pragma unroll
        for (int cb = 0; cb < 2; ++cb) {
          float p0 = __builtin_amdgcn_exp2f(sacc[cb][sl][0]);
          float p1 = __builtin_amdgcn_exp2f(sacc[cb][sl][1]);
          float p2 = __builtin_amdgcn_exp2f(sacc[cb][sl][2]);
          float p3 = __builtin_amdgcn_exp2f(sacc[cb][sl][3]);
          rs[cb] += (p0 + p1) + (p2 + p3);
          union { uint2v u; short4v s; } uu;
          uu.u.x = pack_bf16x2(p0, p1);
          uu.u.y = pack_bf16x2(p2, p3);
          pv[cb][sl] = uu.s;
        }
      }
    }
#pragma unroll
    for (int cb = 0; cb < 2; ++cb) {
      float p0 = __builtin_amdgcn_exp2f(sacc[cb][3][0]);
      float p1 = __builtin_amdgcn_exp2f(sacc[cb][3][1]);
      float p2 = __builtin_amdgcn_exp2f(sacc[cb][3][2]);
      float p3 = __builtin_amdgcn_exp2f(sacc[cb][3][3]);
      rs[cb] += (p0 + p1) + (p2 + p3);
      union { uint2v u; short4v s; } uu;
      uu.u.x = pack_bf16x2(p0, p1);
      uu.u.y = pack_bf16x2(p2, p3);
      pv[cb][3] = uu.s;
    }

    // ---- O^T += V^T P^T : x16 MFMAs, A = V frags (b128 pairs), B = pv regs ----
#pragma unroll
    for (int db = 0; db < 4; ++db) {
#pragma unroll
      for (int sbp = 0; sbp < 2; ++sbp) {
        bf16x8 vv = *(const bf16x8*)&kb[4096 + (db * 2 + sbp) * 512 + lane * 8];
        short4v v0, v1;
        v0[0] = vv[0]; v0[1] = vv[1]; v0[2] = vv[2]; v0[3] = vv[3];
        v1[0] = vv[4]; v1[1] = vv[5]; v1[2] = vv[6]; v1[3] = vv[7];
#pragma unroll
        for (int cb = 0; cb < 2; ++cb) {
          o[cb][db] = __builtin_amdgcn_mfma_f32_16x16x16bf16_1k(v0, pv[cb][sbp * 2 + 0], o[cb][db], 0, 0, 0);
          o[cb][db] = __builtin_amdgcn_mfma_f32_16x16x16bf16_1k(v1, pv[cb][sbp * 2 + 1], o[cb][db], 0, 0, 0);
        }
      }
    }

    // ---- counted-vmcnt barrier: only stage(t+2)'s 4 ops may stay in flight.
    //      Forces stage(t+1) complete; mcur's VGPR deps are compiler-guarded. ----
    asm volatile("s_waitcnt vmcnt(4)" ::: "memory");
    __builtin_amdgcn_s_barrier();
    bR += 1; if (bR == 3) bR = 0;
  }

  // ---- epilogue: full row-sum owned -> normalize in-register, write Out ----
#pragma unroll
  for (int cb = 0; cb < 2; ++cb) {
    float v = rs[cb];
    v += __shfl_xor(v, 16, 64);
    v += __shfl_xor(v, 32, 64);
    const float inv = 1.0f / v;
    const int qrow = row0 + cb * 16 + c;
    float* op = Out + (((size_t)n * Lq + qrow) * Hh + h) * Dd + quad * 4;
#pragma unroll
    for (int db = 0; db < 4; ++db) {
      float4 ov;
      ov.x = o[cb][db][0] * inv; ov.y = o[cb][db][1] * inv;
      ov.z = o[cb][db][2] * inv; ov.w = o[cb][db][3] * inv;
      *(float4*)(op + db * 16) = ov;
    }
  }
}

extern "C" void kernel_launch(void* const* d_in, const int* in_sizes, int n_in,
                              void* d_out, int out_size, void* d_ws, size_t ws_size,
                              hipStream_t stream) {
  const float* Q   = (const float*)d_in[0];
  const float* K   = (const float*)d_in[1];
  const float* V   = (const float*)d_in[2];
  const float* Msk = (const float*)d_in[3];
  float* Out = (float*)d_out;

  short* KVf = (short*)d_ws;                         // 16.78 MB
  short* Mg  = KVf + (size_t)8388608;                // 8.39 MB

  prep_all<<<dim3(KVB + MSKB), dim3(256), 0, stream>>>(K, V, Msk, KVf, Mg);
  attn_fwd<<<dim3(512), dim3(256), 0, stream>>>(Q, KVf, Mg, Out);
}